// Round 3
// baseline (236.051 us; speedup 1.0000x reference)
//
#include <hip/hip_runtime.h>

// DirectionalProcessor: out[b,y,x,o] = bc[o] + sum_{d,c} g[b,y-dy_d,x-dx_d,c] * M_d[c,o]
// with M_d[c,o] = sum_e Wd[d,c,e] * Wc[o, d*256+e]   (Wd/Wc folded -> halves FLOPs)
// B,H,W,C = 16,64,64,256; 8 directions => implicit GEMM [65536 x 2048] @ [2048 x 256].
//
// Pipeline:
//   1) pad_convert: f32 g -> zero-padded bf16 gp[16][66][66][256]
//   2) build_mt:    Mt[d][o][c] (bf16, B^T layout)   [R1: launch_bounds(256,4) to stop spill]
//   3) conv_gemm:   128x128 tile, BK=32, 16x16x32 bf16 MFMA, global_load_lds w=16
//
// R2: (a) XOR bank-swizzle of LDS tiles: slot s of row r holds global chunk s^((r>>1)&3)
//         -> fragment ds_read_b128 cohorts hit 8 distinct 16B bank-groups (was 8-way conflict,
//            SQ_LDS_BANK_CONFLICT=8.4e6).
//     (b) double-buffered DMA: prefetch tile k+2 issued AFTER iter-k barrier -> the
//         compiler's vmcnt(0)-before-s_barrier only drains loads issued a full compute
//         phase earlier; 1 barrier/iter (was 2 + full latency exposure).

typedef unsigned short u16;
typedef unsigned int u32;
typedef __attribute__((ext_vector_type(8))) short bf16x8;   // 8 x bf16 = 4 VGPRs
typedef __attribute__((ext_vector_type(4))) float f32x4;

#define GP_BYTES 35684352    // 16*66*66*256 * 2

__device__ __forceinline__ u16 f2bf(float f) {   // RNE f32->bf16
  u32 u = __float_as_uint(f);
  u32 r = u + 0x7fffu + ((u >> 16) & 1u);
  return (u16)(r >> 16);
}

// ---------------- kernel 1: zero-padded bf16 copy of g ----------------
__global__ __launch_bounds__(256) void pad_convert(const float* __restrict__ g,
                                                   u16* __restrict__ gp) {
  int id = blockIdx.x * 256 + threadIdx.x;      // one thread per 8 channels
  if (id >= 2230272) return;                    // 16*66*66*32
  int c8 = id & 31;
  int t = id >> 5;
  int xx = t % 66;
  int s = t / 66;
  int yy = s % 66;
  int b  = s / 66;
  u32 o0 = 0, o1 = 0, o2 = 0, o3 = 0;
  if (yy != 0 && yy != 65 && xx != 0 && xx != 65) {
    const float* src = g + ((((b << 6) + yy - 1) << 6) + xx - 1) * 256 + (c8 << 3);
    float4 fa = *(const float4*)src;
    float4 fb = *(const float4*)(src + 4);
    o0 = (u32)f2bf(fa.x) | ((u32)f2bf(fa.y) << 16);
    o1 = (u32)f2bf(fa.z) | ((u32)f2bf(fa.w) << 16);
    o2 = (u32)f2bf(fb.x) | ((u32)f2bf(fb.y) << 16);
    o3 = (u32)f2bf(fb.z) | ((u32)f2bf(fb.w) << 16);
  }
  uint4 v; v.x = o0; v.y = o1; v.z = o2; v.w = o3;
  *(uint4*)(gp + (size_t)id * 8) = v;
}

// ---------------- kernel 2: Mt[d][o][c] = sum_e Wd[d][c][e]*Wc[o][d*256+e] ----------------
__global__ __launch_bounds__(256, 4) void build_mt(const float* __restrict__ Wd,
                                                   const float* __restrict__ Wc,
                                                   u16* __restrict__ Mt) {
  __shared__ float sWd[32 * 65];
  __shared__ float sWc[32 * 64];
  int bid = blockIdx.x;            // 8 d * 8 o-tiles * 8 c-tiles = 512
  int d  = bid >> 6;
  int o0 = ((bid >> 3) & 7) << 5;
  int c0 = (bid & 7) << 5;
  int tid = threadIdx.x;
  int cl = tid & 31;
  int ob = (tid >> 5) << 2;
  float a0 = 0, a1 = 0, a2 = 0, a3 = 0;
#pragma unroll 1
  for (int e0 = 0; e0 < 256; e0 += 64) {
    __syncthreads();
#pragma unroll 1
    for (int idx = tid; idx < 2048; idx += 256) {
      int r = idx >> 6, e = idx & 63;
      sWd[r * 65 + e] = Wd[(d * 256 + c0 + r) * 256 + e0 + e];
      sWc[idx]        = Wc[(o0 + r) * 2048 + d * 256 + e0 + e];
    }
    __syncthreads();
#pragma unroll 4
    for (int e = 0; e < 64; ++e) {
      float av = sWd[cl * 65 + e];
      a0 += av * sWc[(ob + 0) * 64 + e];
      a1 += av * sWc[(ob + 1) * 64 + e];
      a2 += av * sWc[(ob + 2) * 64 + e];
      a3 += av * sWc[(ob + 3) * 64 + e];
    }
  }
  u16* dst = Mt + (size_t)(d * 256 + o0 + ob) * 256 + c0 + cl;
  dst[0]   = f2bf(a0);
  dst[256] = f2bf(a1);
  dst[512] = f2bf(a2);
  dst[768] = f2bf(a3);
}

// ---------------- kernel 3: main implicit-GEMM conv ----------------
// directions (dx,dy) -> source offset (ox,oy)=(-dx,-dy); DOFF = (oy*66+ox)*256 in gp elems
__constant__ int DOFF[8] = {16896, 16640, -256, -17152, -16896, -16640, 256, 17152};

__device__ __forceinline__ void async16(const u16* g, u16* l) {
  __builtin_amdgcn_global_load_lds((const __attribute__((address_space(1))) u32*)g,
                                   (__attribute__((address_space(3))) u32*)l, 16, 0, 0);
}

__global__ __launch_bounds__(256) void conv_gemm(const u16* __restrict__ gp,
                                                 const u16* __restrict__ Mt,
                                                 const float* __restrict__ bc,
                                                 float* __restrict__ out) {
  __shared__ __align__(16) u16 As[2][4096];    // 2 x 8 KB (double-buffered)
  __shared__ __align__(16) u16 Bs[2][4096];
  const int tid = threadIdx.x;
  const int n0  = blockIdx.x << 7;             // output-channel block (0 or 128)
  const int bym = blockIdx.y;                  // 512 M-blocks of 128 positions
  const int b   = bym >> 5;
  const int y0  = (bym & 31) << 1;             // 2 image rows per M-block

  const int lane = tid & 63;
  const int wid  = tid >> 6;
  const int wm   = (wid >> 1) << 6;            // wave M offset (0/64)
  const int wn   = (wid & 1) << 6;             // wave N offset (0/64)
  const int quad = lane >> 4;
  const int r16  = lane & 15;

  // staging: thread t holds LDS slot (row=t>>2, s=t&3) at offset t*16B (DMA-forced order).
  // Swizzle: slot s of row r stores global chunk s^((r>>1)&3)  -> conflict-free frag reads.
  const int arow  = tid >> 2;                  // 0..63 == x coordinate
  const int chunk = (tid & 3) ^ ((tid >> 3) & 3);
  const int coff  = chunk << 3;                // channel sub-offset (u16 elems)
  const u16* baseA = gp + ((b * 66 + y0 + 1) * 66 + arow + 1) * 256 + coff;
  const u16* baseB = Mt + (size_t)(n0 + arow) * 256 + coff;
  const int ldso = tid * 8;                    // u16 elems = 16B/thread

  f32x4 acc[4][4] = {};

  auto prefetch = [&](int kt, int bi) {
    const int d  = kt >> 3;
    const int c0 = (kt & 7) << 5;
    const u16* ga = baseA + DOFF[d] + c0;
    async16(ga,            As[bi] + ldso);
    async16(ga + 66 * 256, As[bi] + 2048 + ldso);   // second image row
    const u16* gb = baseB + d * 65536 + c0;
    async16(gb,            Bs[bi] + ldso);
    async16(gb + 64 * 256, Bs[bi] + 2048 + ldso);
  };

  prefetch(0, 0);
  prefetch(1, 1);

  // fragment-read swizzled slot (row>>1)&3 == (r16>>1)&3 since wm,mt*16 are mult of 16
  const int ssl = (quad ^ ((r16 >> 1) & 3)) << 3;   // u16 elems

  __syncthreads();                             // drains tiles 0,1

  for (int kt = 0; kt < 64; ++kt) {
    const u16* Ab = As[kt & 1];
    const u16* Bb = Bs[kt & 1];
    bf16x8 af[4], bfr[4];
#pragma unroll
    for (int mt = 0; mt < 4; ++mt)
      af[mt] = *(const bf16x8*)&Ab[(wm + mt * 16 + r16) * 32 + ssl];
#pragma unroll
    for (int nt = 0; nt < 4; ++nt)
      bfr[nt] = *(const bf16x8*)&Bb[(wn + nt * 16 + r16) * 32 + ssl];
#pragma unroll
    for (int mt = 0; mt < 4; ++mt)
#pragma unroll
      for (int nt = 0; nt < 4; ++nt)
        acc[mt][nt] = __builtin_amdgcn_mfma_f32_16x16x32_bf16(af[mt], bfr[nt], acc[mt][nt], 0, 0, 0);
    __syncthreads();                           // all reads of buf[kt&1] done; drains prefetch kt+1
    if (kt < 62) prefetch(kt + 2, kt & 1);     // in flight during iter kt+1's compute
  }

  // epilogue: C/D layout col=lane&15, row=quad*4+reg
  const int pbase = bym << 7;
#pragma unroll
  for (int nt = 0; nt < 4; ++nt) {
    const int o = n0 + wn + nt * 16 + r16;
    const float bias = bc[o];
#pragma unroll
    for (int mt = 0; mt < 4; ++mt) {
      const int pr = pbase + wm + mt * 16 + quad * 4;
      f32x4 v = acc[mt][nt];
#pragma unroll
      for (int r = 0; r < 4; ++r)
        out[(pr + r) * 256 + o] = v[r] + bias;
    }
  }
}

extern "C" void kernel_launch(void* const* d_in, const int* in_sizes, int n_in,
                              void* d_out, int out_size, void* d_ws, size_t ws_size,
                              hipStream_t stream) {
  const float* g  = (const float*)d_in[0];   // [16,64,64,256] f32
  const float* Wd = (const float*)d_in[1];   // [8,256,256]
  const float* Wc = (const float*)d_in[2];   // [256,2048]
  const float* bc = (const float*)d_in[3];   // [256]
  float* out = (float*)d_out;                // [16,64,64,256] f32
  u16* gp = (u16*)d_ws;                            // 35.7 MB padded bf16 input
  u16* Mt = (u16*)((char*)d_ws + GP_BYTES);        // 1 MB folded weights (B^T)

  pad_convert<<<8712, 256, 0, stream>>>(g, gp);
  build_mt<<<512, 256, 0, stream>>>(Wd, Wc, Mt);
  conv_gemm<<<dim3(2, 512), 256, 0, stream>>>(gp, Mt, bc, out);
}

// Round 4
// 200.312 us; speedup vs baseline: 1.1784x; 1.1784x over previous
//
#include <hip/hip_runtime.h>

// DirectionalProcessor: out[b,y,x,o] = bc[o] + sum_{d,c} g[b,y-dy_d,x-dx_d,c] * M_d[c,o]
// with M_d[c,o] = sum_e Wd[d,c,e]*Wc[o,d*256+e]  (folded -> 68.7 GFLOP implicit GEMM
// [65536 x 2048] @ [2048 x 256], B,H,W,C=16,64,64,256, 8 dirs).
//
// R4: (1) B operand bypasses LDS: build_mt stores folded weights in MFMA-fragment
//         order (Bf), conv loads them as coalesced dwordx4 (L1/L2-hit). LDS reads
//         halved, DMA halved, regs cut (target 4 waves/SIMD incl 64 AGPR acc).
//     (2) XCD-aware block remap: xcd=bid&7, each XCD owns 2 images, n-pairs adjacent
//         -> A rows L2-resident across 8-direction re-reads (FETCH was 5x footprint).
//     (3) build_mt MFMA-ized (was ~25us scalar-FMA; R1's spill fix capped it but
//         it stayed VALU/LDS-heavy).

typedef unsigned short u16;
typedef unsigned int u32;
typedef __attribute__((ext_vector_type(8))) short bf16x8;   // 8 x bf16 = 4 VGPRs
typedef __attribute__((ext_vector_type(4))) float f32x4;

#define GP_BYTES 35684352    // 16*66*66*256 * 2

__device__ __forceinline__ u16 f2bf(float f) {   // RNE f32->bf16
  u32 u = __float_as_uint(f);
  u32 r = u + 0x7fffu + ((u >> 16) & 1u);
  return (u16)(r >> 16);
}
__device__ __forceinline__ u32 pack2(float a, float b) {
  return (u32)f2bf(a) | ((u32)f2bf(b) << 16);
}

// ---------------- kernel 1: zero-padded bf16 copy of g ----------------
__global__ __launch_bounds__(256) void pad_convert(const float* __restrict__ g,
                                                   u16* __restrict__ gp) {
  int id = blockIdx.x * 256 + threadIdx.x;      // one thread per 8 channels
  if (id >= 2230272) return;                    // 16*66*66*32
  int c8 = id & 31;
  int t = id >> 5;
  int xx = t % 66;
  int s = t / 66;
  int yy = s % 66;
  int b  = s / 66;
  u32 o0 = 0, o1 = 0, o2 = 0, o3 = 0;
  if (yy != 0 && yy != 65 && xx != 0 && xx != 65) {
    const float* src = g + ((((b << 6) + yy - 1) << 6) + xx - 1) * 256 + (c8 << 3);
    float4 fa = *(const float4*)src;
    float4 fb = *(const float4*)(src + 4);
    o0 = pack2(fa.x, fa.y);
    o1 = pack2(fa.z, fa.w);
    o2 = pack2(fb.x, fb.y);
    o3 = pack2(fb.z, fb.w);
  }
  uint4 v; v.x = o0; v.y = o1; v.z = o2; v.w = o3;
  *(uint4*)(gp + (size_t)id * 8) = v;
}

// ---------------- kernel 2: MFMA weight fold into fragment-ordered Bf ----------------
// Bf u16 index: ((d*8 + c32)*16 + o16)*512 + lane*8 + e, where lane = (o&15) + ((c>>3)&3)*16
// holds M_d[c = c32*32 + (lane>>4)*8 + e][o = o16*16 + (lane&15)]  (B-operand frag order).
__global__ __launch_bounds__(256) void build_mt(const float* __restrict__ Wd,
                                                const float* __restrict__ Wc,
                                                u16* __restrict__ Bf) {
  __shared__ __align__(16) u16 As[128 * 32];
  __shared__ __align__(16) u16 Bs[128 * 32];
  const int bid = blockIdx.x;          // 32 blocks: 2 n-tiles x (8 d x 2 c-halves)
  const int n0    = (bid & 1) << 7;
  const int mblk  = bid >> 1;          // 0..15
  const int d     = mblk >> 1;
  const int chalf = (mblk & 1) << 7;
  const int tid  = threadIdx.x;
  const int lane = tid & 63, wid = tid >> 6;
  const int wm = (wid >> 1) << 6, wn = (wid & 1) << 6;
  const int quad = lane >> 4, r16 = lane & 15;
  const int srow = tid >> 1, hh = tid & 1;
  const int swz  = (srow >> 1) & 3;
  const int ssl  = (quad ^ ((r16 >> 1) & 3)) << 3;
  f32x4 acc[4][4] = {};

  for (int e0 = 0; e0 < 256; e0 += 32) {
    __syncthreads();
    const float* pa = Wd + (size_t)(d * 256 + chalf + srow) * 256 + e0 + hh * 16;
    const float* pb = Wc + (size_t)(n0 + srow) * 2048 + d * 256 + e0 + hh * 16;
#pragma unroll
    for (int i = 0; i < 2; ++i) {
      float4 a0 = *(const float4*)(pa + i * 8);
      float4 a1 = *(const float4*)(pa + i * 8 + 4);
      float4 b0 = *(const float4*)(pb + i * 8);
      float4 b1 = *(const float4*)(pb + i * 8 + 4);
      uint4 va, vb;
      va.x = pack2(a0.x, a0.y); va.y = pack2(a0.z, a0.w);
      va.z = pack2(a1.x, a1.y); va.w = pack2(a1.z, a1.w);
      vb.x = pack2(b0.x, b0.y); vb.y = pack2(b0.z, b0.w);
      vb.z = pack2(b1.x, b1.y); vb.w = pack2(b1.z, b1.w);
      int slot = (2 * hh + i) ^ swz;
      *(uint4*)&As[srow * 32 + slot * 8] = va;
      *(uint4*)&Bs[srow * 32 + slot * 8] = vb;
    }
    __syncthreads();
    bf16x8 bfr[4];
#pragma unroll
    for (int nt = 0; nt < 4; ++nt)
      bfr[nt] = *(const bf16x8*)&Bs[(wn + nt * 16 + r16) * 32 + ssl];
#pragma unroll
    for (int mt = 0; mt < 4; ++mt) {
      bf16x8 af = *(const bf16x8*)&As[(wm + mt * 16 + r16) * 32 + ssl];
#pragma unroll
      for (int nt = 0; nt < 4; ++nt)
        acc[mt][nt] = __builtin_amdgcn_mfma_f32_16x16x32_bf16(af, bfr[nt], acc[mt][nt], 0, 0, 0);
    }
  }
  // scatter into fragment-ordered Bf (C/D layout: col=o=r16-based, row=c=quad*4+reg)
#pragma unroll
  for (int mt = 0; mt < 4; ++mt) {
#pragma unroll
    for (int nt = 0; nt < 4; ++nt) {
      const int o = n0 + wn + nt * 16 + r16;
      f32x4 v = acc[mt][nt];
#pragma unroll
      for (int r = 0; r < 4; ++r) {
        const int c = chalf + wm + mt * 16 + quad * 4 + r;
        const int lane2 = (o & 15) + (((c >> 3) & 3) << 4);
        const size_t idx = ((size_t)((d * 8 + (c >> 5)) * 16 + (o >> 4)) * 512) + lane2 * 8 + (c & 7);
        Bf[idx] = f2bf(v[r]);
      }
    }
  }
}

// ---------------- kernel 3: main implicit-GEMM conv ----------------
// directions (dx,dy) -> source offset (ox,oy)=(-dx,-dy); DOFF = (oy*66+ox)*256 in gp elems
__constant__ int DOFF[8] = {16896, 16640, -256, -17152, -16896, -16640, 256, 17152};

__device__ __forceinline__ void async16(const u16* g, u16* l) {
  __builtin_amdgcn_global_load_lds((const __attribute__((address_space(1))) u32*)g,
                                   (__attribute__((address_space(3))) u32*)l, 16, 0, 0);
}

__global__ __launch_bounds__(256, 4) void conv_gemm(const u16* __restrict__ gp,
                                                    const u16* __restrict__ Bf,
                                                    const float* __restrict__ bc,
                                                    float* __restrict__ out) {
  __shared__ __align__(16) u16 Asm[2][4096];   // A only: 2 x 8 KB double-buffered
  const int bid = blockIdx.x;                  // 1024 blocks, XCD-aware decode
  const int xcd = bid & 7;
  const int idx = bid >> 3;                    // 0..127 within XCD
  const int b   = (xcd << 1) | (idx >> 6);     // 2 images per XCD
  const int w   = idx & 63;                    // 32 y-blocks x 2 n, n fastest
  const int y0  = (w >> 1) << 1;
  const int n0  = (w & 1) << 7;

  const int tid  = threadIdx.x;
  const int lane = tid & 63;
  const int wid  = tid >> 6;
  const int wm   = (wid >> 1) << 6;
  const int wn   = (wid & 1) << 6;
  const int quad = lane >> 4;
  const int r16  = lane & 15;

  // A staging: thread t -> LDS slot t*16B (+2048 elems for rows 64..127); swizzled chunk
  const int arow  = tid >> 2;
  const int chunk = (tid & 3) ^ ((tid >> 3) & 3);
  const int coff  = chunk << 3;
  const u16* baseA = gp + ((b * 66 + y0 + 1) * 66 + arow + 1) * 256 + coff;
  const int ldso = tid * 8;

  // B fragment base: element run for this (wave, lane); per kt stride 8192 u16
  const u16* baseBf = Bf + (size_t)((n0 >> 4) + (wn >> 4)) * 512 + lane * 8;

  f32x4 acc[4][4] = {};

  auto prefetchA = [&](int kt, int bi) {
    const int off = DOFF[kt >> 3] + ((kt & 7) << 5);
    async16(baseA + off,            Asm[bi] + ldso);
    async16(baseA + off + 66 * 256, Asm[bi] + 2048 + ldso);
  };

  const int ssl = (quad ^ ((r16 >> 1) & 3)) << 3;

  prefetchA(0, 0);
  prefetchA(1, 1);
  bf16x8 bcur[4];
  {
    const u16* bp = baseBf;
#pragma unroll
    for (int nt = 0; nt < 4; ++nt) bcur[nt] = *(const bf16x8*)(bp + nt * 512);
  }
  __syncthreads();                             // drains A(0),A(1),B(0)

  for (int kt = 0; kt < 64; ++kt) {
    // issue next B fragments first (oldest in vmcnt queue after this iter's asyncs)
    const int ktn = (kt < 63) ? kt + 1 : 63;
    const u16* bp = baseBf + (size_t)ktn * 8192;
    bf16x8 bnxt[4];
#pragma unroll
    for (int nt = 0; nt < 4; ++nt) bnxt[nt] = *(const bf16x8*)(bp + nt * 512);

    const u16* Ab = Asm[kt & 1];
#pragma unroll
    for (int mt = 0; mt < 4; ++mt) {
      bf16x8 af = *(const bf16x8*)&Ab[(wm + mt * 16 + r16) * 32 + ssl];
#pragma unroll
      for (int nt = 0; nt < 4; ++nt)
        acc[mt][nt] = __builtin_amdgcn_mfma_f32_16x16x32_bf16(af, bcur[nt], acc[mt][nt], 0, 0, 0);
    }
    __syncthreads();                           // drains A(kt+1) [1 iter old] + B(kt+1)
    if (kt < 62) prefetchA(kt + 2, kt & 1);
#pragma unroll
    for (int nt = 0; nt < 4; ++nt) bcur[nt] = bnxt[nt];
  }

  // epilogue: C/D layout col=lane&15, row=quad*4+reg
  const int pbase = (b * 64 + y0) * 64;
#pragma unroll
  for (int nt = 0; nt < 4; ++nt) {
    const int o = n0 + wn + nt * 16 + r16;
    const float bias = bc[o];
#pragma unroll
    for (int mt = 0; mt < 4; ++mt) {
      const int pr = pbase + wm + mt * 16 + quad * 4;
      f32x4 v = acc[mt][nt];
#pragma unroll
      for (int r = 0; r < 4; ++r)
        out[(size_t)(pr + r) * 256 + o] = v[r] + bias;
    }
  }
}

extern "C" void kernel_launch(void* const* d_in, const int* in_sizes, int n_in,
                              void* d_out, int out_size, void* d_ws, size_t ws_size,
                              hipStream_t stream) {
  const float* g  = (const float*)d_in[0];   // [16,64,64,256] f32
  const float* Wd = (const float*)d_in[1];   // [8,256,256]
  const float* Wc = (const float*)d_in[2];   // [256,2048]
  const float* bc = (const float*)d_in[3];   // [256]
  float* out = (float*)d_out;                // [16,64,64,256] f32
  u16* gp = (u16*)d_ws;                            // 35.7 MB padded bf16 input
  u16* Bf = (u16*)((char*)d_ws + GP_BYTES);        // 1 MB fragment-ordered weights

  pad_convert<<<8712, 256, 0, stream>>>(g, gp);
  build_mt<<<32, 256, 0, stream>>>(Wd, Wc, Bf);
  conv_gemm<<<1024, 256, 0, stream>>>(gp, Bf, bc, out);
}

// Round 5
// 197.774 us; speedup vs baseline: 1.1935x; 1.0128x over previous
//
#include <hip/hip_runtime.h>

// DirectionalProcessor: out[b,y,x,o] = bc[o] + sum_{d,c} g[b,y-dy_d,x-dx_d,c] * M_d[c,o]
// with M_d[c,o] = sum_e Wd[d,c,e]*Wc[o,d*256+e]  (folded -> 68.7 GFLOP implicit GEMM
// [65536 x 2048] @ [2048 x 256], B,H,W,C=16,64,64,256, 8 dirs).
//
// R5: AITER-style K-loop. __syncthreads() (= s_waitcnt vmcnt(0) + s_barrier) was
// draining the just-issued A-DMAs every iter (~115k bubble cyc/CU; MfmaUtil 36%).
// Now: 4-stage LDS, raw s_barrier + s_waitcnt vmcnt(2) per iter; A-DMA for kt+2
// stays in flight across the barrier (issued after this iter's ds_reads so the
// compiler's alias-conservative waitcnt can't force a drain). FIFO proof: queue at
// the wait is [A(kt+1)x2, B(kt+1)x4, A(kt+2)x2]; vmcnt(2) retires exactly the
// first six -> next iter's LDS reads and bcur are safe, newest DMAs keep flying.

typedef unsigned short u16;
typedef unsigned int u32;
typedef __attribute__((ext_vector_type(8))) short bf16x8;   // 8 x bf16 = 4 VGPRs
typedef __attribute__((ext_vector_type(4))) float f32x4;

#define GP_BYTES 35684352    // 16*66*66*256 * 2

__device__ __forceinline__ u16 f2bf(float f) {   // RNE f32->bf16
  u32 u = __float_as_uint(f);
  u32 r = u + 0x7fffu + ((u >> 16) & 1u);
  return (u16)(r >> 16);
}
__device__ __forceinline__ u32 pack2(float a, float b) {
  return (u32)f2bf(a) | ((u32)f2bf(b) << 16);
}

// ---------------- kernel 1: zero-padded bf16 copy of g ----------------
__global__ __launch_bounds__(256) void pad_convert(const float* __restrict__ g,
                                                   u16* __restrict__ gp) {
  int id = blockIdx.x * 256 + threadIdx.x;      // one thread per 8 channels
  if (id >= 2230272) return;                    // 16*66*66*32
  int c8 = id & 31;
  int t = id >> 5;
  int xx = t % 66;
  int s = t / 66;
  int yy = s % 66;
  int b  = s / 66;
  u32 o0 = 0, o1 = 0, o2 = 0, o3 = 0;
  if (yy != 0 && yy != 65 && xx != 0 && xx != 65) {
    const float* src = g + ((((b << 6) + yy - 1) << 6) + xx - 1) * 256 + (c8 << 3);
    float4 fa = *(const float4*)src;
    float4 fb = *(const float4*)(src + 4);
    o0 = pack2(fa.x, fa.y);
    o1 = pack2(fa.z, fa.w);
    o2 = pack2(fb.x, fb.y);
    o3 = pack2(fb.z, fb.w);
  }
  uint4 v; v.x = o0; v.y = o1; v.z = o2; v.w = o3;
  *(uint4*)(gp + (size_t)id * 8) = v;
}

// ---------------- kernel 2: MFMA weight fold into fragment-ordered Bf ----------------
// Bf u16 index: ((d*8 + c32)*16 + o16)*512 + lane*8 + e, where lane = (o&15) + ((c>>3)&3)*16
// holds M_d[c = c32*32 + (lane>>4)*8 + e][o = o16*16 + (lane&15)]  (B-operand frag order).
__global__ __launch_bounds__(256) void build_mt(const float* __restrict__ Wd,
                                                const float* __restrict__ Wc,
                                                u16* __restrict__ Bf) {
  __shared__ __align__(16) u16 As[128 * 32];
  __shared__ __align__(16) u16 Bs[128 * 32];
  const int bid = blockIdx.x;          // 32 blocks: 2 n-tiles x (8 d x 2 c-halves)
  const int n0    = (bid & 1) << 7;
  const int mblk  = bid >> 1;          // 0..15
  const int d     = mblk >> 1;
  const int chalf = (mblk & 1) << 7;
  const int tid  = threadIdx.x;
  const int lane = tid & 63, wid = tid >> 6;
  const int wm = (wid >> 1) << 6, wn = (wid & 1) << 6;
  const int quad = lane >> 4, r16 = lane & 15;
  const int srow = tid >> 1, hh = tid & 1;
  const int swz  = (srow >> 1) & 3;
  const int ssl  = (quad ^ ((r16 >> 1) & 3)) << 3;
  f32x4 acc[4][4] = {};

  for (int e0 = 0; e0 < 256; e0 += 32) {
    __syncthreads();
    const float* pa = Wd + (size_t)(d * 256 + chalf + srow) * 256 + e0 + hh * 16;
    const float* pb = Wc + (size_t)(n0 + srow) * 2048 + d * 256 + e0 + hh * 16;
#pragma unroll
    for (int i = 0; i < 2; ++i) {
      float4 a0 = *(const float4*)(pa + i * 8);
      float4 a1 = *(const float4*)(pa + i * 8 + 4);
      float4 b0 = *(const float4*)(pb + i * 8);
      float4 b1 = *(const float4*)(pb + i * 8 + 4);
      uint4 va, vb;
      va.x = pack2(a0.x, a0.y); va.y = pack2(a0.z, a0.w);
      va.z = pack2(a1.x, a1.y); va.w = pack2(a1.z, a1.w);
      vb.x = pack2(b0.x, b0.y); vb.y = pack2(b0.z, b0.w);
      vb.z = pack2(b1.x, b1.y); vb.w = pack2(b1.z, b1.w);
      int slot = (2 * hh + i) ^ swz;
      *(uint4*)&As[srow * 32 + slot * 8] = va;
      *(uint4*)&Bs[srow * 32 + slot * 8] = vb;
    }
    __syncthreads();
    bf16x8 bfr[4];
#pragma unroll
    for (int nt = 0; nt < 4; ++nt)
      bfr[nt] = *(const bf16x8*)&Bs[(wn + nt * 16 + r16) * 32 + ssl];
#pragma unroll
    for (int mt = 0; mt < 4; ++mt) {
      bf16x8 af = *(const bf16x8*)&As[(wm + mt * 16 + r16) * 32 + ssl];
#pragma unroll
      for (int nt = 0; nt < 4; ++nt)
        acc[mt][nt] = __builtin_amdgcn_mfma_f32_16x16x32_bf16(af, bfr[nt], acc[mt][nt], 0, 0, 0);
    }
  }
  // scatter into fragment-ordered Bf (C/D layout: col=o=r16-based, row=c=quad*4+reg)
#pragma unroll
  for (int mt = 0; mt < 4; ++mt) {
#pragma unroll
    for (int nt = 0; nt < 4; ++nt) {
      const int o = n0 + wn + nt * 16 + r16;
      f32x4 v = acc[mt][nt];
#pragma unroll
      for (int r = 0; r < 4; ++r) {
        const int c = chalf + wm + mt * 16 + quad * 4 + r;
        const int lane2 = (o & 15) + (((c >> 3) & 3) << 4);
        const size_t idx = ((size_t)((d * 8 + (c >> 5)) * 16 + (o >> 4)) * 512) + lane2 * 8 + (c & 7);
        Bf[idx] = f2bf(v[r]);
      }
    }
  }
}

// ---------------- kernel 3: main implicit-GEMM conv ----------------
// directions (dx,dy) -> source offset (ox,oy)=(-dx,-dy); DOFF = (oy*66+ox)*256 in gp elems
__constant__ int DOFF[8] = {16896, 16640, -256, -17152, -16896, -16640, 256, 17152};

__device__ __forceinline__ void async16(const u16* g, u16* l) {
  __builtin_amdgcn_global_load_lds((const __attribute__((address_space(1))) u32*)g,
                                   (__attribute__((address_space(3))) u32*)l, 16, 0, 0);
}

__global__ __launch_bounds__(256, 4) void conv_gemm(const u16* __restrict__ gp,
                                                    const u16* __restrict__ Bf,
                                                    const float* __restrict__ bc,
                                                    float* __restrict__ out) {
  __shared__ __align__(16) u16 Asm[4][4096];   // 4-stage, 32 KB total
  const int bid = blockIdx.x;                  // 1024 blocks, XCD-aware decode
  const int xcd = bid & 7;
  const int idx = bid >> 3;                    // 0..127 within XCD
  const int b   = (xcd << 1) | (idx >> 6);     // 2 images per XCD
  const int w   = idx & 63;                    // 32 y-blocks x 2 n, n fastest
  const int y0  = (w >> 1) << 1;
  const int n0  = (w & 1) << 7;

  const int tid  = threadIdx.x;
  const int lane = tid & 63;
  const int wid  = tid >> 6;
  const int wm   = (wid >> 1) << 6;
  const int wn   = (wid & 1) << 6;
  const int quad = lane >> 4;
  const int r16  = lane & 15;

  // A staging: thread t -> LDS slot t*16B (+2048 elems for rows 64..127); swizzled chunk
  const int arow  = tid >> 2;
  const int chunk = (tid & 3) ^ ((tid >> 3) & 3);
  const int coff  = chunk << 3;
  const u16* baseA = gp + ((b * 66 + y0 + 1) * 66 + arow + 1) * 256 + coff;
  const int ldso = tid * 8;

  // B fragment base: element run for this (wave, lane); per kt stride 8192 u16
  const u16* baseBf = Bf + (size_t)((n0 >> 4) + (wn >> 4)) * 512 + lane * 8;

  const int ssl = (quad ^ ((r16 >> 1) & 3)) << 3;

  f32x4 acc[4][4] = {};
  bf16x8 bcur[4], bnxt[4];

  auto issueA = [&](int kt) {                  // DMA tile kt into Asm[kt&3]
    const int off = DOFF[kt >> 3] + ((kt & 7) << 5);
    async16(baseA + off,            Asm[kt & 3] + ldso);
    async16(baseA + off + 66 * 256, Asm[kt & 3] + 2048 + ldso);
  };
  auto loadB = [&](int kt, bf16x8* dst) {
    const u16* bp = baseBf + (size_t)kt * 8192;
#pragma unroll
    for (int nt = 0; nt < 4; ++nt) dst[nt] = *(const bf16x8*)(bp + nt * 512);
  };
  auto readA = [&](int kt, bf16x8* af) {
    const u16* Ab = Asm[kt & 3];
#pragma unroll
    for (int mt = 0; mt < 4; ++mt)
      af[mt] = *(const bf16x8*)&Ab[(wm + mt * 16 + r16) * 32 + ssl];
  };
  auto domfma = [&](const bf16x8* af, const bf16x8* bb) {
#pragma unroll
    for (int mt = 0; mt < 4; ++mt)
#pragma unroll
      for (int nt = 0; nt < 4; ++nt)
        acc[mt][nt] = __builtin_amdgcn_mfma_f32_16x16x32_bf16(af[mt], bb[nt], acc[mt][nt], 0, 0, 0);
  };

  // prologue: queue = [B(0)x4, A(0)x2, A(1)x2]; vmcnt(2) -> B(0),A(0) done, A(1) flying
  loadB(0, bcur);
  issueA(0);
  issueA(1);
  asm volatile("s_waitcnt vmcnt(2)" ::: "memory");
  asm volatile("s_barrier" ::: "memory");

#pragma unroll 2
  for (int kt = 0; kt < 62; ++kt) {
    loadB(kt + 1, bnxt);                       // issued before this iter's DMA
    bf16x8 af[4];
    readA(kt, af);                             // ds_reads before new DMA (no alias drain)
    issueA(kt + 2);
    domfma(af, bcur);
    // queue: [A(kt+1)x2, B(kt+1)x4, A(kt+2)x2] -> vmcnt(2) retires first 6
    asm volatile("s_waitcnt vmcnt(2)" ::: "memory");
    asm volatile("s_barrier" ::: "memory");
#pragma unroll
    for (int nt = 0; nt < 4; ++nt) bcur[nt] = bnxt[nt];
  }
  // kt = 62: no more A to issue
  {
    loadB(63, bnxt);
    bf16x8 af[4];
    readA(62, af);
    domfma(af, bcur);
    asm volatile("s_waitcnt vmcnt(0)" ::: "memory");
    asm volatile("s_barrier" ::: "memory");
#pragma unroll
    for (int nt = 0; nt < 4; ++nt) bcur[nt] = bnxt[nt];
  }
  // kt = 63
  {
    bf16x8 af[4];
    readA(63, af);
    domfma(af, bcur);
  }

  // epilogue: C/D layout col=lane&15, row=quad*4+reg
  const int pbase = (b * 64 + y0) * 64;
#pragma unroll
  for (int nt = 0; nt < 4; ++nt) {
    const int o = n0 + wn + nt * 16 + r16;
    const float bias = bc[o];
#pragma unroll
    for (int mt = 0; mt < 4; ++mt) {
      const int pr = pbase + wm + mt * 16 + quad * 4;
      f32x4 v = acc[mt][nt];
#pragma unroll
      for (int r = 0; r < 4; ++r)
        out[(size_t)(pr + r) * 256 + o] = v[r] + bias;
    }
  }
}

extern "C" void kernel_launch(void* const* d_in, const int* in_sizes, int n_in,
                              void* d_out, int out_size, void* d_ws, size_t ws_size,
                              hipStream_t stream) {
  const float* g  = (const float*)d_in[0];   // [16,64,64,256] f32
  const float* Wd = (const float*)d_in[1];   // [8,256,256]
  const float* Wc = (const float*)d_in[2];   // [256,2048]
  const float* bc = (const float*)d_in[3];   // [256]
  float* out = (float*)d_out;                // [16,64,64,256] f32
  u16* gp = (u16*)d_ws;                            // 35.7 MB padded bf16 input
  u16* Bf = (u16*)((char*)d_ws + GP_BYTES);        // 1 MB fragment-ordered weights

  pad_convert<<<8712, 256, 0, stream>>>(g, gp);
  build_mt<<<32, 256, 0, stream>>>(Wd, Wc, Bf);
  conv_gemm<<<1024, 256, 0, stream>>>(gp, Bf, bc, out);
}